// Round 1
// baseline (192.520 us; speedup 1.0000x reference)
//
#include <hip/hip_runtime.h>
#include <hip/hip_fp16.h>

#define T_LEN 32768
#define ADIM  512
#define NDEC  1024
#define KTAPS 31

// workspace float offsets (no aliasing — ws is huge)
#define WS_BASE 0        // 512   : dec_proj[a] + conv-bias proj        (k0->k1)
#define WS_G    512      // 7936 u32 : Gf16[k][a/2] packed half2        (k0->k1)
#define WS_SARR 16384    // 32768 : sv[t] = 2*(e[t]+mask[t])            (k1->k3)
#define WS_BMAX 49152    // 512   : per-k1-block online max
#define WS_BSUM 49664    // 512   : per-k1-block online sumexp
#define WS_SSUM 50176    // 1     : S = sum of clipped u                (k3->k4)
#define WS_U    50432    // 32768 : unnormalized u[t]                   (k3->k4)
#define WS_CREP 83968    // 16384 : 32 replicated c~ accumulators (zeroed by k1 blocks 0..15)

__device__ __forceinline__ float fast_tanh(float x) {
    // tanh(x) = 1 - 2/(exp(2x)+1); ~1e-7 abs err vs 3.5e-4 threshold
    float e = __expf(2.0f * x);
    return 1.0f - 2.0f * __builtin_amdgcn_rcpf(e + 1.0f);
}

__device__ __forceinline__ float uniform_f(float v) {
    return __uint_as_float(__builtin_amdgcn_readfirstlane(__float_as_uint(v)));
}

// ---------------- K0: dec_proj+bias -> base[512]; Gf16[31][256] packed; zero SSUM -----
__global__ __launch_bounds__(256) void k0_prep(
        const float* __restrict__ dec_z, const float* __restrict__ conv_w,
        const float* __restrict__ conv_b, const float* __restrict__ W_att,
        const float* __restrict__ W_dec, float* __restrict__ ws) {
    int b = blockIdx.x, tid = threadIdx.x;
    int lane = tid & 63, wave = tid >> 6;
    if (b < 64) {
        // 8 a's per block, wave handles 2 (64-lane dot over 1024)
        for (int s = 0; s < 2; ++s) {
            int a = b * 8 + wave * 2 + s;
            float sum = 0.f;
            #pragma unroll
            for (int i = 0; i < 16; ++i)
                sum += W_dec[a * NDEC + i * 64 + lane] * dec_z[i * 64 + lane];
            #pragma unroll
            for (int off = 32; off > 0; off >>= 1) sum += __shfl_xor(sum, off);
            if (lane == 0) {
                float bias = 0.f;
                #pragma unroll
                for (int c = 0; c < 32; ++c) bias += conv_b[c] * W_att[a * 32 + c];
                ws[WS_BASE + a] = sum + bias;
            }
        }
    } else if (b < 64 + KTAPS) {
        // G[k][a] = sum_c conv_w[c,k]*W_att[a,c], packed as half2 (a even=lo, odd=hi).
        // |G| ~ 0.06-0.5: comfortably f16-normal; propagated output err ~1e-8.
        int k = b - 64;
        int a0 = 2 * tid;
        float g0 = 0.f, g1 = 0.f;
        #pragma unroll
        for (int c = 0; c < 32; ++c) {
            float w = conv_w[c * KTAPS + k];
            g0 += w * W_att[a0 * 32 + c];
            g1 += w * W_att[(a0 + 1) * 32 + c];
        }
        __half2 h = __floats2half2_rn(g0, g1);
        ((unsigned int*)ws)[WS_G + k * 256 + tid] = *(unsigned int*)&h;
    } else {
        if (tid == 0) ws[WS_SSUM] = 0.f;
    }
}

// ---------------- K1: sv[t]=2*(e[t]+mask[t]) + per-block online (max,sumexp) ----------
// 512 blocks x 1024 thr (16 waves). Waves 0..7 own a-half 0, waves 8..15 own a-half 1
// of the SAME 8-t group (wpair = wave&7); partial energies combined via 256 B LDS.
// G is f16-packed -> LDS 31.7 KB -> 2 blocks/CU x 16 waves = 32 waves/CU (100% occ);
// the old fp32-G 512-thr version was capped at 16 waves/CU (Occupancy 35%, VALU 40%).
// bounds(1024,8) -> 64-VGPR cap. acc[j] is initialized to p[j]+base so the p regs die
// immediately (old code held p[8]+acc[8] live = would spill at 64-cap; R5 proved spill
// = 5x regression). Blocks 0..15 zero the c-replicas (kernel boundary = fence; NO
// __threadfence — R6's per-block device fence cost 115 us in k3).
__global__ __launch_bounds__(1024, 8) void k1_energy(
        const float* __restrict__ att_prev, const float* __restrict__ pre,
        const float* __restrict__ mask, const float* __restrict__ W_g,
        const float* __restrict__ b_g, float* __restrict__ ws) {
    __shared__ unsigned int Gs[KTAPS * 256];   // 31744 B f16-packed
    __shared__ float ap_s[96];
    __shared__ float eP[64];                   // half-1 partial energies
    __shared__ float wm[8], wz[8];
    int tid = threadIdx.x, lane = tid & 63, wave = tid >> 6;
    int wpair = wave & 7, ah = wave >> 3;      // ah = which a-half this wave owns
    int t0 = blockIdx.x * 64;

    // zero c~ replicas for k3 (32*512 = 16384 floats over blocks 0..15 x 1024 thr)
    if (blockIdx.x < 16) ws[WS_CREP + blockIdx.x * 1024 + tid] = 0.f;

    // stage packed G (7936 u32 = 1984 uint4)
    const uint4* Gsrc = (const uint4*)((const unsigned int*)ws + WS_G);
    uint4* Gdst = (uint4*)Gs;
    #pragma unroll
    for (int i = 0; i < 2; ++i) {
        int idx = tid + i * 1024;
        if (idx < 1984) Gdst[idx] = Gsrc[idx];
    }
    if (tid < 94) {
        int g = t0 - 15 + tid;
        ap_s[tid] = (g >= 0 && g < T_LEN) ? att_prev[g] : 0.f;
    }
    __syncthreads();

    float bg = b_g[0];
    int tb_local = wpair * 8;
    int tb = t0 + tb_local;

    // wave-uniform ap window -> SGPRs (zero VGPR cost)
    float ap_u[38];
    #pragma unroll
    for (int i = 0; i < 38; ++i) ap_u[i] = uniform_f(ap_s[tb_local + i]);

    int aa = ah * 256 + 4 * lane;
    float4 base = *(const float4*)(ws + WS_BASE + aa);

    // acc[j] = pre + base  (p dies immediately -> peak live ~48 VGPR)
    float4 acc[8];
    #pragma unroll
    for (int j = 0; j < 8; ++j) {
        float4 p = *(const float4*)(pre + (size_t)(tb + j) * ADIM + aa);
        acc[j] = make_float4(p.x + base.x, p.y + base.y, p.z + base.z, p.w + base.w);
    }

    #pragma unroll
    for (int k = 0; k < KTAPS; ++k) {
        uint2 g2 = *(const uint2*)&Gs[k * 256 + ah * 128 + 2 * lane];
        __half2 h0 = *(const __half2*)&g2.x;
        __half2 h1 = *(const __half2*)&g2.y;
        float gx = __low2float(h0), gy = __high2float(h0);
        float gz = __low2float(h1), gw = __high2float(h1);
        #pragma unroll
        for (int j = 0; j < 8; ++j) {
            float apv = ap_u[j + k];
            acc[j].x = fmaf(apv, gx, acc[j].x);
            acc[j].y = fmaf(apv, gy, acc[j].y);
            acc[j].z = fmaf(apv, gz, acc[j].z);
            acc[j].w = fmaf(apv, gw, acc[j].w);
        }
    }

    float4 wg = *(const float4*)(W_g + aa);
    float e8[8];
    #pragma unroll
    for (int j = 0; j < 8; ++j) {
        float s = 0.f;
        s = fmaf(fast_tanh(acc[j].x), wg.x, s);
        s = fmaf(fast_tanh(acc[j].y), wg.y, s);
        s = fmaf(fast_tanh(acc[j].z), wg.z, s);
        s = fmaf(fast_tanh(acc[j].w), wg.w, s);
        #pragma unroll
        for (int off = 32; off > 0; off >>= 1) s += __shfl_xor(s, off);
        e8[j] = s;
    }

    if (ah == 1 && lane == 0) {
        #pragma unroll
        for (int j = 0; j < 8; ++j) eP[tb_local + j] = e8[j];
    }
    __syncthreads();

    if (ah == 0) {
        float m_run = -1e30f, z_run = 0.f;
        #pragma unroll
        for (int j = 0; j < 8; ++j) {
            int t = tb + j;
            float sv = 2.0f * (e8[j] + eP[tb_local + j] + bg + mask[t]);
            float mn = fmaxf(m_run, sv);
            z_run = z_run * __expf(m_run - mn) + __expf(sv - mn);
            m_run = mn;
            if (lane == 0) ws[WS_SARR + t] = sv;
        }
        if (lane == 0) { wm[wpair] = m_run; wz[wpair] = z_run; }
    }
    __syncthreads();
    if (tid == 0) {
        float M = wm[0], Z = wz[0];
        #pragma unroll
        for (int w = 1; w < 8; ++w) {
            float mn = fmaxf(M, wm[w]);
            Z = Z * __expf(M - mn) + wz[w] * __expf(wm[w] - mn);
            M = mn;
        }
        ws[WS_BMAX + blockIdx.x] = M;
        ws[WS_BSUM + blockIdx.x] = Z;
    }
}

// ---------------- K3: redundant (M,Z) combine; u[t]; c~ partials; S -------------------
// 1024 blocks x 512 thr. Prologue: 8 waves butterfly-combine the 512 (M,Z) pairs.
// 4 teams of 128; team covers 8 t's x 512 a's with unnormalized u; team-0 atomics
// into one of 32 replicas (no fence). Wave-0 lanes 0..31 write u[t] + atomic S.
__global__ __launch_bounds__(512) void k3_context(
        const float* __restrict__ att_prev, const float* __restrict__ enc_h,
        float* __restrict__ ws) {
    __shared__ float wmz[16];
    __shared__ float cbuf[4 * 512];
    int tid = threadIdx.x, lane = tid & 63, wave = tid >> 6;

    // combine 512 (M,Z) pairs: wave w owns chunk [64w, 64w+64)
    float m = ws[WS_BMAX + wave * 64 + lane];
    float z = ws[WS_BSUM + wave * 64 + lane];
    #pragma unroll
    for (int off = 32; off > 0; off >>= 1) {
        float mo = __shfl_xor(m, off), zo = __shfl_xor(z, off);
        float mn = fmaxf(m, mo);
        z = z * __expf(m - mn) + zo * __expf(mo - mn);
        m = mn;
    }
    if (lane == 0) { wmz[wave] = m; wmz[8 + wave] = z; }
    __syncthreads();
    float M = wmz[0], Z = wmz[8];
    #pragma unroll
    for (int w = 1; w < 8; ++w) {
        float mn = fmaxf(M, wmz[w]);
        Z = Z * __expf(M - mn) + wmz[8 + w] * __expf(wmz[w] - mn);
        M = mn;
    }
    float invZ = 1.0f / Z;

    int t0 = blockIdx.x * 32;
    int team = tid >> 7, l = tid & 127;
    int a4 = 4 * l;
    int tbase = t0 + team * 8;
    float4 acc = make_float4(0.f, 0.f, 0.f, 0.f);
    #pragma unroll
    for (int i = 0; i < 8; ++i) {
        int t = tbase + i;
        float ap0 = att_prev[t];
        float apm = (t > 0) ? att_prev[t - 1] : 0.f;
        float u = fmaxf((ap0 + apm) * __expf(ws[WS_SARR + t] - M) * invZ, 1e-6f);
        float4 e = *(const float4*)(enc_h + (size_t)t * ADIM + a4);
        acc.x = fmaf(u, e.x, acc.x);
        acc.y = fmaf(u, e.y, acc.y);
        acc.z = fmaf(u, e.z, acc.z);
        acc.w = fmaf(u, e.w, acc.w);
    }
    if (team != 0) *(float4*)&cbuf[team * 512 + a4] = acc;

    // wave 0, lanes 0..31: write unnormalized u[t] for this block + S partial
    if (tid < 32) {
        int t = t0 + tid;
        float ap0 = att_prev[t];
        float apm = (t > 0) ? att_prev[t - 1] : 0.f;
        float u = fmaxf((ap0 + apm) * __expf(ws[WS_SARR + t] - M) * invZ, 1e-6f);
        ws[WS_U + t] = u;
        float s = u;
        #pragma unroll
        for (int off = 16; off > 0; off >>= 1) s += __shfl_xor(s, off, 32);
        if (tid == 0) atomicAdd(&ws[WS_SSUM], s);
    }
    __syncthreads();
    if (team == 0) {
        float4 b1 = *(const float4*)&cbuf[1 * 512 + a4];
        float4 b2 = *(const float4*)&cbuf[2 * 512 + a4];
        float4 b3 = *(const float4*)&cbuf[3 * 512 + a4];
        float* rep = ws + WS_CREP + (blockIdx.x & 31) * 512;
        atomicAdd(&rep[a4 + 0], acc.x + b1.x + b2.x + b3.x);
        atomicAdd(&rep[a4 + 1], acc.y + b1.y + b2.y + b3.y);
        atomicAdd(&rep[a4 + 2], acc.z + b1.z + b2.z + b3.z);
        atomicAdd(&rep[a4 + 3], acc.w + b1.w + b2.w + b3.w);
    }
}

// ---------------- K4: c = (sum replicas)/S -> out[0:512]; w = u/S -> out[512:] --------
__global__ __launch_bounds__(512) void k4_final(
        const float* __restrict__ ws, float* __restrict__ out) {
    int b = blockIdx.x, tid = threadIdx.x;
    float invS = 1.0f / ws[WS_SSUM];
    if (b == 0) {
        float acc = 0.f;
        #pragma unroll
        for (int r = 0; r < 32; ++r) acc += ws[WS_CREP + r * 512 + tid];
        out[tid] = acc * invS;
    } else {
        int i = (b - 1) * 512 + tid;
        out[512 + i] = ws[WS_U + i] * invS;
    }
}

extern "C" void kernel_launch(void* const* d_in, const int* in_sizes, int n_in,
                              void* d_out, int out_size, void* d_ws, size_t ws_size,
                              hipStream_t stream) {
    const float* dec_z    = (const float*)d_in[0];
    const float* att_prev = (const float*)d_in[1];
    const float* pre      = (const float*)d_in[2];
    const float* enc_h    = (const float*)d_in[3];
    const float* mask     = (const float*)d_in[4];
    const float* conv_w   = (const float*)d_in[5];
    const float* conv_b   = (const float*)d_in[6];
    const float* W_att    = (const float*)d_in[7];
    const float* W_dec    = (const float*)d_in[8];
    const float* W_g      = (const float*)d_in[9];
    const float* b_g      = (const float*)d_in[10];
    float* out = (float*)d_out;
    float* ws  = (float*)d_ws;

    k0_prep   <<<96,   256,  0, stream>>>(dec_z, conv_w, conv_b, W_att, W_dec, ws);
    k1_energy <<<512,  1024, 0, stream>>>(att_prev, pre, mask, W_g, b_g, ws);
    k3_context<<<1024, 512,  0, stream>>>(att_prev, enc_h, ws);
    k4_final  <<<65,   512,  0, stream>>>(ws, out);
}

// Round 2
// 186.674 us; speedup vs baseline: 1.0313x; 1.0313x over previous
//
#include <hip/hip_runtime.h>

#define T_LEN 32768
#define ADIM  512
#define NDEC  1024
#define KTAPS 31

// workspace float offsets (no aliasing — ws is huge)
#define WS_BASE 0        // 512   : dec_proj[a] + conv-bias proj        (k0->k1)
#define WS_G    512      // 8192 floats = 32KB: G as bf16 MFMA B-fragments (k0->k1)
#define WS_SARR 16384    // 32768 : sv[t] = 2*(e[t]+mask[t])            (k1->k3)
#define WS_BMAX 49152    // 512   : per-k1-block online max
#define WS_BSUM 49664    // 512   : per-k1-block online sumexp
#define WS_SSUM 50176    // 1     : S = sum of clipped u                (k3->k4)
#define WS_U    50432    // 32768 : unnormalized u[t]                   (k3->k4)
#define WS_CREP 83968    // 16384 : 32 replicated c~ accumulators (zeroed by k1 blocks 0..31)

typedef __attribute__((ext_vector_type(8))) short bf16x8;
typedef __attribute__((ext_vector_type(4))) float f32x4;

__device__ __forceinline__ float fast_tanh(float x) {
    // tanh(x) = 1 - 2/(exp(2x)+1); ~1e-7 abs err vs 3.5e-4 threshold
    float e = __expf(2.0f * x);
    return 1.0f - 2.0f * __builtin_amdgcn_rcpf(e + 1.0f);
}

__device__ __forceinline__ unsigned short f2bf(float f) {
    // f32 -> bf16 round-to-nearest-even
    unsigned u = __float_as_uint(f);
    return (unsigned short)((u + 0x7FFFu + ((u >> 16) & 1u)) >> 16);
}

// ---------------- K0: dec_proj+bias -> base[512]; G B-fragments (bf16); zero SSUM -----
// G-fragment layout for mfma_f32_16x16x32_bf16 B-operand: per a-tile `at` (16 a's),
// lane l holds B[k][col] for col = l&15, k = 8*(l>>4)+i (i=0..7 contiguous bf16).
// Stored at u16 index (at*64 + l)*8 + i. k=31 is the zero pad tap (K=32).
__global__ __launch_bounds__(256) void k0_prep(
        const float* __restrict__ dec_z, const float* __restrict__ conv_w,
        const float* __restrict__ conv_b, const float* __restrict__ W_att,
        const float* __restrict__ W_dec, float* __restrict__ ws) {
    int b = blockIdx.x, tid = threadIdx.x;
    int lane = tid & 63, wave = tid >> 6;
    if (b < 64) {
        if (b == 0 && tid == 0) ws[WS_SSUM] = 0.f;
        // 8 a's per block, wave handles 2 (64-lane dot over 1024)
        for (int s = 0; s < 2; ++s) {
            int a = b * 8 + wave * 2 + s;
            float sum = 0.f;
            #pragma unroll
            for (int i = 0; i < 16; ++i)
                sum += W_dec[a * NDEC + i * 64 + lane] * dec_z[i * 64 + lane];
            #pragma unroll
            for (int off = 32; off > 0; off >>= 1) sum += __shfl_xor(sum, off);
            if (lane == 0) {
                float bias = 0.f;
                #pragma unroll
                for (int c = 0; c < 32; ++c) bias += conv_b[c] * W_att[a * 32 + c];
                ws[WS_BASE + a] = sum + bias;
            }
        }
    } else {
        int k = b - 64;                 // 0..31 (31 = zero pad)
        unsigned short* Gf = (unsigned short*)(ws + WS_G);
        for (int s = 0; s < 2; ++s) {
            int a = 2 * tid + s;
            float g = 0.f;
            if (k < KTAPS) {
                #pragma unroll
                for (int c = 0; c < 32; ++c)
                    g += conv_w[c * KTAPS + k] * W_att[a * 32 + c];
            }
            int at = a >> 4, col = a & 15;
            int l = col | ((k >> 3) << 4), i = k & 7;
            Gf[(at * 64 + l) * 8 + i] = f2bf(g);
        }
    }
}

// ---------------- K1: MFMA conv + tanh-dot energies + per-block online (max,sumexp) ---
// 512 blocks x 512 thr (8 waves). wave = ah*4 + tt: tt = t-tile (16 t's), ah = a-half
// (256 a's = 16 a-tiles). Conv via mfma_f32_16x16x32_bf16: D[t][a] = sum_k ap*G, with
// base[a] folded into C-init. A-frag (built once/wave from LDS ap window): row=lane&15,
// k=8*(lane>>4)+i. B-frags read straight from L2-hot ws (no LDS staging). Epilogue per
// a-tile: +pre, tanh, dot W_g. This removes the ~992 v_fma/wave conv (R1 showed k1 is
// VALU-issue bound at 40% busy: occupancy 78% didn't help). R5 lesson: no spill —
// unroll 4 keeps ~60 live VGPRs under the (512,4)=128 cap.
__global__ __launch_bounds__(512, 4) void k1_energy(
        const float* __restrict__ att_prev, const float* __restrict__ pre,
        const float* __restrict__ mask, const float* __restrict__ W_g,
        const float* __restrict__ b_g, float* __restrict__ ws) {
    __shared__ float ap_s[96];
    __shared__ float eP[2][64];
    int tid = threadIdx.x, lane = tid & 63, wave = tid >> 6;
    int tt = wave & 3, ah = wave >> 2;
    int t0 = blockIdx.x * 64;

    // zero c~ replicas for k3 (kernel boundary = the fence; NO __threadfence here —
    // R6's per-block device fence cost 115 us in k3)
    if (blockIdx.x < 32) ws[WS_CREP + blockIdx.x * 512 + tid] = 0.f;

    // stage ap window t0-15 .. t0+79 (95 floats used: A needs idx up to 94)
    if (tid < 96) {
        int g = t0 - 15 + tid;
        ap_s[tid] = (g >= 0 && g < T_LEN) ? att_prev[g] : 0.f;
    }
    __syncthreads();

    int row = lane & 15, g4 = lane >> 4;

    // A fragment: A[t][k] = ap_s[tt*16 + t + k]; lane: t=row, k=8*g4+i
    bf16x8 afrag;
    int aidx = tt * 16 + row + g4 * 8;
    #pragma unroll
    for (int i = 0; i < 8; ++i) afrag[i] = (short)f2bf(ap_s[aidx + i]);

    const unsigned short* Gf = (const unsigned short*)(ws + WS_G);
    float e_acc[4] = {0.f, 0.f, 0.f, 0.f};
    int tbase = t0 + tt * 16 + g4 * 4;

    #pragma unroll 4
    for (int p = 0; p < 16; ++p) {
        int at = ah * 16 + p;
        int ac = at * 16 + row;                                   // this lane's a
        bf16x8 bfrag = *(const bf16x8*)(Gf + (size_t)(at * 64 + lane) * 8);
        float bs = ws[WS_BASE + ac];
        f32x4 c = {bs, bs, bs, bs};
        c = __builtin_amdgcn_mfma_f32_16x16x32_bf16(afrag, bfrag, c, 0, 0, 0);
        float wgv = W_g[ac];
        // D layout (m89-verified): col=lane&15 (=a), row=(lane>>4)*4+r (=t)
        #pragma unroll
        for (int r = 0; r < 4; ++r) {
            float pv = pre[(size_t)(tbase + r) * ADIM + ac];
            e_acc[r] = fmaf(fast_tanh(c[r] + pv), wgv, e_acc[r]);
        }
    }

    // sum over the 16 a-columns within each lane group
    #pragma unroll
    for (int r = 0; r < 4; ++r) {
        float s = e_acc[r];
        s += __shfl_xor(s, 1); s += __shfl_xor(s, 2);
        s += __shfl_xor(s, 4); s += __shfl_xor(s, 8);
        e_acc[r] = s;
    }
    if (row == 0) {
        #pragma unroll
        for (int r = 0; r < 4; ++r) eP[ah][tt * 16 + g4 * 4 + r] = e_acc[r];
    }
    __syncthreads();

    // wave 0: combine a-halves, write sv, 64-lane online (M,Z) butterfly
    if (wave == 0) {
        int t = t0 + lane;
        float e = eP[0][lane] + eP[1][lane];
        float sv = 2.0f * (e + b_g[0] + mask[t]);
        ws[WS_SARR + t] = sv;
        float m = sv, z = 1.0f;
        #pragma unroll
        for (int off = 32; off > 0; off >>= 1) {
            float mo = __shfl_xor(m, off), zo = __shfl_xor(z, off);
            float mn = fmaxf(m, mo);
            z = z * __expf(m - mn) + zo * __expf(mo - mn);
            m = mn;
        }
        if (lane == 0) { ws[WS_BMAX + blockIdx.x] = m; ws[WS_BSUM + blockIdx.x] = z; }
    }
}

// ---------------- K3: redundant (M,Z) combine; u[t]; c~ partials; S -------------------
// 1024 blocks x 512 thr. Prologue: 8 waves butterfly-combine the 512 (M,Z) pairs.
// 4 teams of 128; team covers 8 t's x 512 a's with unnormalized u; team-0 atomics
// into one of 32 replicas (no fence). Wave-0 lanes 0..31 write u[t] + atomic S.
__global__ __launch_bounds__(512) void k3_context(
        const float* __restrict__ att_prev, const float* __restrict__ enc_h,
        float* __restrict__ ws) {
    __shared__ float wmz[16];
    __shared__ float cbuf[4 * 512];
    int tid = threadIdx.x, lane = tid & 63, wave = tid >> 6;

    // combine 512 (M,Z) pairs: wave w owns chunk [64w, 64w+64)
    float m = ws[WS_BMAX + wave * 64 + lane];
    float z = ws[WS_BSUM + wave * 64 + lane];
    #pragma unroll
    for (int off = 32; off > 0; off >>= 1) {
        float mo = __shfl_xor(m, off), zo = __shfl_xor(z, off);
        float mn = fmaxf(m, mo);
        z = z * __expf(m - mn) + zo * __expf(mo - mn);
        m = mn;
    }
    if (lane == 0) { wmz[wave] = m; wmz[8 + wave] = z; }
    __syncthreads();
    float M = wmz[0], Z = wmz[8];
    #pragma unroll
    for (int w = 1; w < 8; ++w) {
        float mn = fmaxf(M, wmz[w]);
        Z = Z * __expf(M - mn) + wmz[8 + w] * __expf(wmz[w] - mn);
        M = mn;
    }
    float invZ = 1.0f / Z;

    int t0 = blockIdx.x * 32;
    int team = tid >> 7, l = tid & 127;
    int a4 = 4 * l;
    int tbase = t0 + team * 8;
    float4 acc = make_float4(0.f, 0.f, 0.f, 0.f);
    #pragma unroll
    for (int i = 0; i < 8; ++i) {
        int t = tbase + i;
        float ap0 = att_prev[t];
        float apm = (t > 0) ? att_prev[t - 1] : 0.f;
        float u = fmaxf((ap0 + apm) * __expf(ws[WS_SARR + t] - M) * invZ, 1e-6f);
        float4 e = *(const float4*)(enc_h + (size_t)t * ADIM + a4);
        acc.x = fmaf(u, e.x, acc.x);
        acc.y = fmaf(u, e.y, acc.y);
        acc.z = fmaf(u, e.z, acc.z);
        acc.w = fmaf(u, e.w, acc.w);
    }
    if (team != 0) *(float4*)&cbuf[team * 512 + a4] = acc;

    // wave 0, lanes 0..31: write unnormalized u[t] for this block + S partial
    if (tid < 32) {
        int t = t0 + tid;
        float ap0 = att_prev[t];
        float apm = (t > 0) ? att_prev[t - 1] : 0.f;
        float u = fmaxf((ap0 + apm) * __expf(ws[WS_SARR + t] - M) * invZ, 1e-6f);
        ws[WS_U + t] = u;
        float s = u;
        #pragma unroll
        for (int off = 16; off > 0; off >>= 1) s += __shfl_xor(s, off, 32);
        if (tid == 0) atomicAdd(&ws[WS_SSUM], s);
    }
    __syncthreads();
    if (team == 0) {
        float4 b1 = *(const float4*)&cbuf[1 * 512 + a4];
        float4 b2 = *(const float4*)&cbuf[2 * 512 + a4];
        float4 b3 = *(const float4*)&cbuf[3 * 512 + a4];
        float* rep = ws + WS_CREP + (blockIdx.x & 31) * 512;
        atomicAdd(&rep[a4 + 0], acc.x + b1.x + b2.x + b3.x);
        atomicAdd(&rep[a4 + 1], acc.y + b1.y + b2.y + b3.y);
        atomicAdd(&rep[a4 + 2], acc.z + b1.z + b2.z + b3.z);
        atomicAdd(&rep[a4 + 3], acc.w + b1.w + b2.w + b3.w);
    }
}

// ---------------- K4: c = (sum replicas)/S -> out[0:512]; w = u/S -> out[512:] --------
__global__ __launch_bounds__(512) void k4_final(
        const float* __restrict__ ws, float* __restrict__ out) {
    int b = blockIdx.x, tid = threadIdx.x;
    float invS = 1.0f / ws[WS_SSUM];
    if (b == 0) {
        float acc = 0.f;
        #pragma unroll
        for (int r = 0; r < 32; ++r) acc += ws[WS_CREP + r * 512 + tid];
        out[tid] = acc * invS;
    } else {
        int i = (b - 1) * 512 + tid;
        out[512 + i] = ws[WS_U + i] * invS;
    }
}

extern "C" void kernel_launch(void* const* d_in, const int* in_sizes, int n_in,
                              void* d_out, int out_size, void* d_ws, size_t ws_size,
                              hipStream_t stream) {
    const float* dec_z    = (const float*)d_in[0];
    const float* att_prev = (const float*)d_in[1];
    const float* pre      = (const float*)d_in[2];
    const float* enc_h    = (const float*)d_in[3];
    const float* mask     = (const float*)d_in[4];
    const float* conv_w   = (const float*)d_in[5];
    const float* conv_b   = (const float*)d_in[6];
    const float* W_att    = (const float*)d_in[7];
    const float* W_dec    = (const float*)d_in[8];
    const float* W_g      = (const float*)d_in[9];
    const float* b_g      = (const float*)d_in[10];
    float* out = (float*)d_out;
    float* ws  = (float*)d_ws;

    k0_prep   <<<96,   256, 0, stream>>>(dec_z, conv_w, conv_b, W_att, W_dec, ws);
    k1_energy <<<512,  512, 0, stream>>>(att_prev, pre, mask, W_g, b_g, ws);
    k3_context<<<1024, 512, 0, stream>>>(att_prev, enc_h, ws);
    k4_final  <<<65,   512, 0, stream>>>(ws, out);
}

// Round 3
// 183.273 us; speedup vs baseline: 1.0505x; 1.0186x over previous
//
#include <hip/hip_runtime.h>

#define T_LEN 32768
#define ADIM  512
#define NDEC  1024
#define KTAPS 31

// workspace float offsets (no aliasing — ws is huge)
#define WS_BASE 0        // 512   : dec_proj[a] + conv-bias proj        (k0->k1)
#define WS_G    512      // 8192 floats = 32KB: G as bf16 MFMA B-fragments (k0->k1)
#define WS_SARR 16384    // 32768 : sv[t] = 2*(e[t]+mask[t])            (k1->k3)
#define WS_BMAX 49152    // 2048  : per-k1-block online max   (2048 blocks now)
#define WS_BSUM 51200    // 2048  : per-k1-block online sumexp
#define WS_SSUM 53248    // 1     : S = sum of clipped u                (k3->k4)
#define WS_U    53504    // 32768 : unnormalized u[t]                   (k3->k4)
#define WS_CREP 86272    // 16384 : 32 replicated c~ accumulators (zeroed by k1 blocks 0..31)

typedef __attribute__((ext_vector_type(8))) short bf16x8;
typedef __attribute__((ext_vector_type(4))) float f32x4;

__device__ __forceinline__ float fast_tanh(float x) {
    // tanh(x) = 1 - 2/(exp(2x)+1); ~1e-7 abs err vs 3.5e-4 threshold
    float e = __expf(2.0f * x);
    return 1.0f - 2.0f * __builtin_amdgcn_rcpf(e + 1.0f);
}

__device__ __forceinline__ unsigned short f2bf(float f) {
    // f32 -> bf16 round-to-nearest-even
    unsigned u = __float_as_uint(f);
    return (unsigned short)((u + 0x7FFFu + ((u >> 16) & 1u)) >> 16);
}

// ---------------- K0: dec_proj+bias -> base[512]; G B-fragments (bf16); zero SSUM -----
// G-fragment layout for mfma_f32_16x16x32_bf16 B-operand: per a-tile `at` (16 a's),
// lane l holds B[k][col] for col = l&15, k = 8*(l>>4)+i (i=0..7 contiguous bf16).
// Stored at u16 index (at*64 + l)*8 + i. k=31 is the zero pad tap (K=32).
__global__ __launch_bounds__(256) void k0_prep(
        const float* __restrict__ dec_z, const float* __restrict__ conv_w,
        const float* __restrict__ conv_b, const float* __restrict__ W_att,
        const float* __restrict__ W_dec, float* __restrict__ ws) {
    int b = blockIdx.x, tid = threadIdx.x;
    int lane = tid & 63, wave = tid >> 6;
    if (b < 64) {
        if (b == 0 && tid == 0) ws[WS_SSUM] = 0.f;
        // 8 a's per block, wave handles 2 (64-lane dot over 1024)
        for (int s = 0; s < 2; ++s) {
            int a = b * 8 + wave * 2 + s;
            float sum = 0.f;
            #pragma unroll
            for (int i = 0; i < 16; ++i)
                sum += W_dec[a * NDEC + i * 64 + lane] * dec_z[i * 64 + lane];
            #pragma unroll
            for (int off = 32; off > 0; off >>= 1) sum += __shfl_xor(sum, off);
            if (lane == 0) {
                float bias = 0.f;
                #pragma unroll
                for (int c = 0; c < 32; ++c) bias += conv_b[c] * W_att[a * 32 + c];
                ws[WS_BASE + a] = sum + bias;
            }
        }
    } else {
        int k = b - 64;                 // 0..31 (31 = zero pad)
        unsigned short* Gf = (unsigned short*)(ws + WS_G);
        for (int s = 0; s < 2; ++s) {
            int a = 2 * tid + s;
            float g = 0.f;
            if (k < KTAPS) {
                #pragma unroll
                for (int c = 0; c < 32; ++c)
                    g += conv_w[c * KTAPS + k] * W_att[a * 32 + c];
            }
            int at = a >> 4, col = a & 15;
            int l = col | ((k >> 3) << 4), i = k & 7;
            Gf[(at * 64 + l) * 8 + i] = f2bf(g);
        }
    }
}

// ---------------- K1 v3: DMA-staged pre + MFMA conv + tanh-dot energies --------------
// DIAGNOSIS (R0-R2): three different k1 structures (VALU-heavy/occupancy-2x/MFMA) all
// ran 40-44 us = 1.6 TB/s effective read of the 64 MB `pre` stream — register-load
// MSHR-limited (need ~22 KB/CU in flight for 6.3 TB/s; reg loads track too few misses).
// FIX: stage pre via __builtin_amdgcn_global_load_lds (VGPR-free, deep vmcnt queue —
// the m97-proven high-BW read path). 2048 blocks x 512 thr; block = 16 t x 512 a;
// LDS tile 16x512 f32 = 32 KB (under 64 KB static cap). 8 waves: wave stages rows
// {2w,2w+1} (4 x 1KB DMAs), then owns a-octant wave*64 (4 MFMA a-tiles).
// Cross-block wave overlap on a CU pipelines stage vs compute.
__global__ __launch_bounds__(512, 6) void k1_energy(
        const float* __restrict__ att_prev, const float* __restrict__ pre,
        const float* __restrict__ mask, const float* __restrict__ W_g,
        const float* __restrict__ b_g, float* __restrict__ ws) {
    __shared__ float pre_s[16 * ADIM];   // 32 KB
    __shared__ float ap_s[48];
    __shared__ float eP[8][16];
    int tid = threadIdx.x, lane = tid & 63, wave = tid >> 6;
    int t0 = blockIdx.x * 16;

    // zero c~ replicas for k3 (kernel boundary = the fence; NO __threadfence here —
    // R6's per-block device fence cost 115 us in k3)
    if (blockIdx.x < 32) ws[WS_CREP + blockIdx.x * 512 + tid] = 0.f;

    // async-stage the 16x512 pre tile: wave w -> rows {2w, 2w+1}, 2 half-rows each.
    // global src is per-lane (base + lane*16B); LDS dest is wave-uniform (HW adds
    // lane*16). 4 outstanding 1KB DMAs per wave, zero VGPR cost.
    {
        const float* grow = pre + (size_t)(t0 + 2 * wave) * ADIM + lane * 4;
        float* lrow = &pre_s[(2 * wave) * ADIM];
        #pragma unroll
        for (int r = 0; r < 2; ++r) {
            #pragma unroll
            for (int h = 0; h < 2; ++h) {
                __builtin_amdgcn_global_load_lds(
                    (const __attribute__((address_space(1))) void*)(grow + r * ADIM + h * 256),
                    (__attribute__((address_space(3))) void*)(lrow + r * ADIM + h * 256),
                    16, 0, 0);
            }
        }
    }
    if (tid < 48) {
        int g = t0 - 15 + tid;
        ap_s[tid] = (g >= 0 && g < T_LEN) ? att_prev[g] : 0.f;
    }
    __syncthreads();   // compiler emits vmcnt(0)+lgkmcnt(0) drain before barrier

    int row = lane & 15, g4 = lane >> 4;

    // A fragment (R2-verified layout): A[t][k] = ap_s[t + k]; lane: t=row, k=8*g4+i
    bf16x8 afrag;
    int aidx = row + g4 * 8;
    #pragma unroll
    for (int i = 0; i < 8; ++i) afrag[i] = (short)f2bf(ap_s[aidx + i]);

    const unsigned short* Gf = (const unsigned short*)(ws + WS_G);
    float e_acc[4] = {0.f, 0.f, 0.f, 0.f};

    #pragma unroll 2
    for (int p = 0; p < 4; ++p) {
        int at = wave * 4 + p;
        int ac = at * 16 + row;                                   // this lane's a
        bf16x8 bfrag = *(const bf16x8*)(Gf + (size_t)(at * 64 + lane) * 8);
        float bs = ws[WS_BASE + ac];
        f32x4 c = {bs, bs, bs, bs};
        c = __builtin_amdgcn_mfma_f32_16x16x32_bf16(afrag, bfrag, c, 0, 0, 0);
        float wgv = W_g[ac];
        // D layout (m89-verified): col=lane&15 (=a), row=(lane>>4)*4+r (=t)
        #pragma unroll
        for (int r = 0; r < 4; ++r) {
            float pv = pre_s[(g4 * 4 + r) * ADIM + ac];
            e_acc[r] = fmaf(fast_tanh(c[r] + pv), wgv, e_acc[r]);
        }
    }

    // sum over the 16 a-columns within each lane group
    #pragma unroll
    for (int r = 0; r < 4; ++r) {
        float s = e_acc[r];
        s += __shfl_xor(s, 1); s += __shfl_xor(s, 2);
        s += __shfl_xor(s, 4); s += __shfl_xor(s, 8);
        e_acc[r] = s;
    }
    if (row == 0) {
        #pragma unroll
        for (int r = 0; r < 4; ++r) eP[wave][g4 * 4 + r] = e_acc[r];
    }
    __syncthreads();

    // wave 0: combine 8 a-octants, write sv, masked 64-lane online (M,Z) butterfly
    if (wave == 0) {
        float sv = -1e30f, z0 = 0.f;
        if (lane < 16) {
            float e = 0.f;
            #pragma unroll
            for (int q = 0; q < 8; ++q) e += eP[q][lane];
            int t = t0 + lane;
            sv = 2.0f * (e + b_g[0] + mask[t]);
            ws[WS_SARR + t] = sv;
            z0 = 1.0f;
        }
        float m = sv, z = z0;
        #pragma unroll
        for (int off = 32; off > 0; off >>= 1) {
            float mo = __shfl_xor(m, off), zo = __shfl_xor(z, off);
            float mn = fmaxf(m, mo);
            z = z * __expf(m - mn) + zo * __expf(mo - mn);
            m = mn;
        }
        if (lane == 0) { ws[WS_BMAX + blockIdx.x] = m; ws[WS_BSUM + blockIdx.x] = z; }
    }
}

// ---------------- K3: redundant (M,Z) combine; u[t]; c~ partials; S -------------------
// 1024 blocks x 512 thr. Prologue: each lane serially combines 4 of the 2048 (M,Z)
// pairs, then 8-wave butterfly. 4 teams of 128; team covers 8 t's x 512 a's with
// unnormalized u; team-0 atomics into one of 32 replicas (no fence). Wave-0 lanes
// 0..31 write u[t] + atomic S.
__global__ __launch_bounds__(512) void k3_context(
        const float* __restrict__ att_prev, const float* __restrict__ enc_h,
        float* __restrict__ ws) {
    __shared__ float wmz[16];
    __shared__ float cbuf[4 * 512];
    int tid = threadIdx.x, lane = tid & 63, wave = tid >> 6;

    // combine 2048 (M,Z) pairs: wave w owns chunk [256w, 256w+256), 4 per lane
    float m = -1e30f, z = 0.f;
    int base = wave * 256 + lane;
    #pragma unroll
    for (int q = 0; q < 4; ++q) {
        float mo = ws[WS_BMAX + base + q * 64], zo = ws[WS_BSUM + base + q * 64];
        float mn = fmaxf(m, mo);
        z = z * __expf(m - mn) + zo * __expf(mo - mn);
        m = mn;
    }
    #pragma unroll
    for (int off = 32; off > 0; off >>= 1) {
        float mo = __shfl_xor(m, off), zo = __shfl_xor(z, off);
        float mn = fmaxf(m, mo);
        z = z * __expf(m - mn) + zo * __expf(mo - mn);
        m = mn;
    }
    if (lane == 0) { wmz[wave] = m; wmz[8 + wave] = z; }
    __syncthreads();
    float M = wmz[0], Z = wmz[8];
    #pragma unroll
    for (int w = 1; w < 8; ++w) {
        float mn = fmaxf(M, wmz[w]);
        Z = Z * __expf(M - mn) + wmz[8 + w] * __expf(wmz[w] - mn);
        M = mn;
    }
    float invZ = 1.0f / Z;

    int t0 = blockIdx.x * 32;
    int team = tid >> 7, l = tid & 127;
    int a4 = 4 * l;
    int tbase = t0 + team * 8;
    float4 acc = make_float4(0.f, 0.f, 0.f, 0.f);
    #pragma unroll
    for (int i = 0; i < 8; ++i) {
        int t = tbase + i;
        float ap0 = att_prev[t];
        float apm = (t > 0) ? att_prev[t - 1] : 0.f;
        float u = fmaxf((ap0 + apm) * __expf(ws[WS_SARR + t] - M) * invZ, 1e-6f);
        float4 e = *(const float4*)(enc_h + (size_t)t * ADIM + a4);
        acc.x = fmaf(u, e.x, acc.x);
        acc.y = fmaf(u, e.y, acc.y);
        acc.z = fmaf(u, e.z, acc.z);
        acc.w = fmaf(u, e.w, acc.w);
    }
    if (team != 0) *(float4*)&cbuf[team * 512 + a4] = acc;

    // wave 0, lanes 0..31: write unnormalized u[t] for this block + S partial
    if (tid < 32) {
        int t = t0 + tid;
        float ap0 = att_prev[t];
        float apm = (t > 0) ? att_prev[t - 1] : 0.f;
        float u = fmaxf((ap0 + apm) * __expf(ws[WS_SARR + t] - M) * invZ, 1e-6f);
        ws[WS_U + t] = u;
        float s = u;
        #pragma unroll
        for (int off = 16; off > 0; off >>= 1) s += __shfl_xor(s, off, 32);
        if (tid == 0) atomicAdd(&ws[WS_SSUM], s);
    }
    __syncthreads();
    if (team == 0) {
        float4 b1 = *(const float4*)&cbuf[1 * 512 + a4];
        float4 b2 = *(const float4*)&cbuf[2 * 512 + a4];
        float4 b3 = *(const float4*)&cbuf[3 * 512 + a4];
        float* rep = ws + WS_CREP + (blockIdx.x & 31) * 512;
        atomicAdd(&rep[a4 + 0], acc.x + b1.x + b2.x + b3.x);
        atomicAdd(&rep[a4 + 1], acc.y + b1.y + b2.y + b3.y);
        atomicAdd(&rep[a4 + 2], acc.z + b1.z + b2.z + b3.z);
        atomicAdd(&rep[a4 + 3], acc.w + b1.w + b2.w + b3.w);
    }
}

// ---------------- K4: c = (sum replicas)/S -> out[0:512]; w = u/S -> out[512:] --------
__global__ __launch_bounds__(512) void k4_final(
        const float* __restrict__ ws, float* __restrict__ out) {
    int b = blockIdx.x, tid = threadIdx.x;
    float invS = 1.0f / ws[WS_SSUM];
    if (b == 0) {
        float acc = 0.f;
        #pragma unroll
        for (int r = 0; r < 32; ++r) acc += ws[WS_CREP + r * 512 + tid];
        out[tid] = acc * invS;
    } else {
        int i = (b - 1) * 512 + tid;
        out[512 + i] = ws[WS_U + i] * invS;
    }
}

extern "C" void kernel_launch(void* const* d_in, const int* in_sizes, int n_in,
                              void* d_out, int out_size, void* d_ws, size_t ws_size,
                              hipStream_t stream) {
    const float* dec_z    = (const float*)d_in[0];
    const float* att_prev = (const float*)d_in[1];
    const float* pre      = (const float*)d_in[2];
    const float* enc_h    = (const float*)d_in[3];
    const float* mask     = (const float*)d_in[4];
    const float* conv_w   = (const float*)d_in[5];
    const float* conv_b   = (const float*)d_in[6];
    const float* W_att    = (const float*)d_in[7];
    const float* W_dec    = (const float*)d_in[8];
    const float* W_g      = (const float*)d_in[9];
    const float* b_g      = (const float*)d_in[10];
    float* out = (float*)d_out;
    float* ws  = (float*)d_ws;

    k0_prep   <<<96,   256, 0, stream>>>(dec_z, conv_w, conv_b, W_att, W_dec, ws);
    k1_energy <<<2048, 512, 0, stream>>>(att_prev, pre, mask, W_g, b_g, ws);
    k3_context<<<1024, 512, 0, stream>>>(att_prev, enc_h, ws);
    k4_final  <<<65,   512, 0, stream>>>(ws, out);
}